// Round 12
// baseline (134.946 us; speedup 1.0000x reference)
//
#include <hip/hip_runtime.h>
#include <hip/hip_bf16.h>

#define Bdim 4
#define Tdim 2048
#define Wdim 1024
#define Kdim 7
#define Gdim 8
#define Cg   128
#define Hdim 64   // W / SE_R
#define TT   32   // t-rows per conv block

typedef __attribute__((ext_vector_type(8))) short short8v;
typedef __attribute__((ext_vector_type(4))) float float4v;

__device__ __forceinline__ short f2bf(float x) {          // RNE
    union { float f; unsigned u; } v; v.f = x;
    unsigned r = v.u + 0x7fff + ((v.u >> 16) & 1);
    return (short)(r >> 16);
}

__device__ __forceinline__ unsigned pack2bf(float lo, float hi) {  // round-half-up
    return __builtin_amdgcn_perm(__float_as_uint(hi) + 0x8000u,
                                 __float_as_uint(lo) + 0x8000u, 0x07060302u);
}

// lerp two bf16x8 (as uint4) in fp32, repack to bf16x8
__device__ __forceinline__ short8v lerp_pack(uint4 a, uint4 b, float f) {
    union { uint4 u; short8v s; } r;
    const unsigned* pa = (const unsigned*)&a;
    const unsigned* pb = (const unsigned*)&b;
    unsigned* pr = (unsigned*)&r.u;
#pragma unroll
    for (int d = 0; d < 4; d++) {
        float alo = __uint_as_float(pa[d] << 16);
        float ahi = __uint_as_float(pa[d] & 0xffff0000u);
        float blo = __uint_as_float(pb[d] << 16);
        float bhi = __uint_as_float(pb[d] & 0xffff0000u);
        float rlo = alo + f * (blo - alo);
        float rhi = ahi + f * (bhi - ahi);
        pr[d] = pack2bf(rlo, rhi);
    }
    return r.s;
}

// ---------------- K_pre: weights->bf16 linear + zero rowstat + offsets GEMV + h->bf16 ----------------
__global__ __launch_bounds__(256) void k_pre(const float* __restrict__ conv_w,
                                             short* __restrict__ Wtb,
                                             const float* __restrict__ h,
                                             const float* __restrict__ offset_w,
                                             const float* __restrict__ offset_b,
                                             float* __restrict__ pos,
                                             ushort* __restrict__ h16,
                                             float* __restrict__ rowstat) {
    int tid = threadIdx.x;
    if (blockIdx.x < 448) {
        if (blockIdx.x < 64) rowstat[blockIdx.x * 256 + tid] = 0.f;
        int i = blockIdx.x * 256 + tid;
        int cb = i & 15;
        int o = (i >> 4) & 127;
        int gk = i >> 11;                            // g*7 + k
        int k = gk % Kdim, g = gk / Kdim;
        const float* src = conv_w + ((size_t)(g * Cg + o) * Cg + cb * 8) * Kdim + k;
        short8v pk;
#pragma unroll
        for (int j = 0; j < 8; j++) pk[j] = f2bf(src[(size_t)j * Kdim]);
        short8v* Wtb8 = (short8v*)Wtb;
        Wtb8[(size_t)gk * 2048 + o * 16 + cb] = pk;   // linear layout
        return;
    }
    // offsets + h16: one wave per row, 4 rows per block
    int lane = tid & 63, wv = tid >> 6;
    int bt = (blockIdx.x - 448) * 4 + wv;            // b*T + t
    int t = bt & (Tdim - 1);
    const float* row = h + (size_t)bt * Wdim;
    float acc[Kdim];
#pragma unroll
    for (int k = 0; k < Kdim; k++) acc[k] = 0.f;
#pragma unroll
    for (int j = 0; j < 4; j++) {
        int c = lane * 4 + j * 256;
        float4 hv = *(const float4*)(row + c);
        const float* ow = offset_w + (size_t)c * Kdim;
#pragma unroll
        for (int k = 0; k < Kdim; k++)
            acc[k] += hv.x * ow[k] + hv.y * ow[Kdim + k] + hv.z * ow[2 * Kdim + k]
                    + hv.w * ow[3 * Kdim + k];
        ushort4 hp;
        hp.x = (ushort)f2bf(hv.x); hp.y = (ushort)f2bf(hv.y);
        hp.z = (ushort)f2bf(hv.z); hp.w = (ushort)f2bf(hv.w);
        *(ushort4*)(h16 + (size_t)bt * Wdim + c) = hp;
    }
#pragma unroll
    for (int k = 0; k < Kdim; k++) {
#pragma unroll
        for (int m = 32; m > 0; m >>= 1) acc[k] += __shfl_xor(acc[k], m);
    }
    if (lane < Kdim) {
        float o = acc[lane] + offset_b[lane];
        float base = (float)t + (float)(lane - 3);
        float p = fminf(fmaxf(base + o, 0.f), (float)(Tdim - 1));
        pos[bt * Kdim + lane] = p;
    }
}

// ---------------- K2: deformable grouped conv; TLP-first (small LDS, high occupancy) ----------------
// grid 2048 = g-major XCD swizzle: blk = g*256 + (b*64 + tc); 256 thr = 4 waves; wave = 32t x 32o
__global__ __launch_bounds__(256, 5) void k_conv(const ushort* __restrict__ h16,
                                                 const short* __restrict__ Wtb,
                                                 const float* __restrict__ conv_b,
                                                 const float* __restrict__ pos,
                                                 ushort* __restrict__ y16,
                                                 float* __restrict__ rowstat) {
    __shared__ __align__(16) char smem[17408];       // 16KB (A-stage 8KB / epilogue 16KB) + 1KB pos
    short8v* sA  = (short8v*)smem;                   // TT*16 units = 8 KB
    float*  posl = (float*)(smem + 16384);           // TT*8 = 1 KB

    int blk = blockIdx.x;
    int g    = blk >> 8;                 // XCD-major: same g -> same XCD L2 (B slice hot)
    int rest = blk & 255;
    int b    = rest >> 6;
    int tc   = rest & 63;
    int t0 = tc * TT;
    int tid = threadIdx.x;
    int lane = tid & 63, wv = tid >> 6;
    int r15 = lane & 15, q = lane >> 4;

    const ushort* hb = h16 + (size_t)(b * Tdim) * Wdim + g * Cg;
    const short8v* WtbV = (const short8v*)Wtb + (size_t)(g * Kdim) * 2048;

    int scb = tid & 15;          // staging 16B col-block
    int sr  = tid >> 4;          // staging row 0..15 (and +16)

    // pos tile -> LDS
    if (tid < TT * Kdim) {
        int r = tid / 7, kk = tid - r * 7;
        posl[r * 8 + kk] = pos[(b * Tdim + t0) * Kdim + tid];
    }
    __syncthreads();             // posl ready before ANY gather reads it (R11 race fix)

    float4v acc[2][2];
#pragma unroll
    for (int ts = 0; ts < 2; ts++)
#pragma unroll
        for (int os = 0; os < 2; os++) acc[ts][os] = (float4v){0.f, 0.f, 0.f, 0.f};

#pragma unroll 1
    for (int k = 0; k < Kdim; k++) {
        // ---- B(k) fragments (L2-resident, lands under gather/lerp) ----
        short8v bfr[8];
#pragma unroll
        for (int j = 0; j < 8; j++) {
            int os = j >> 2, kk = j & 3;
            bfr[j] = WtbV[(size_t)k * 2048 + (wv * 32 + os * 16 + r15) * 16 + kk * 4 + q];
        }
        // ---- gather + lerp 2 units/thread ----
        short8v w0, w1;
        {
            int r = sr;
            float p = posl[r * 8 + k];
            int p0 = (int)p; float f = p - (float)p0;
            int p1 = min(p0 + 1, Tdim - 1);
            uint4 lo = *(const uint4*)(hb + (size_t)p0 * Wdim + scb * 8);
            uint4 hi = *(const uint4*)(hb + (size_t)p1 * Wdim + scb * 8);
            w0 = lerp_pack(lo, hi, f);
        }
        {
            int r = sr + 16;
            float p = posl[r * 8 + k];
            int p0 = (int)p; float f = p - (float)p0;
            int p1 = min(p0 + 1, Tdim - 1);
            uint4 lo = *(const uint4*)(hb + (size_t)p0 * Wdim + scb * 8);
            uint4 hi = *(const uint4*)(hb + (size_t)p1 * Wdim + scb * 8);
            w1 = lerp_pack(lo, hi, f);
        }
        __syncthreads();                 // WAR: prev compute done reading sA
        sA[sr * 16 + (scb ^ (sr & 7))] = w0;
        sA[(sr + 16) * 16 + (scb ^ ((sr + 16) & 7))] = w1;
        __syncthreads();                 // RAW: tile ready
        // ---- compute(k): 2 ts x (4 ds_read + 8 MFMA) ----
#pragma unroll
        for (int ts = 0; ts < 2; ts++) {
            int r = ts * 16 + r15;
            short8v af[4];
#pragma unroll
            for (int kk = 0; kk < 4; kk++)
                af[kk] = sA[r * 16 + ((kk * 4 + q) ^ (r15 & 7))];
#pragma unroll
            for (int kk = 0; kk < 4; kk++)
#pragma unroll
                for (int os = 0; os < 2; os++)
                    acc[ts][os] = __builtin_amdgcn_mfma_f32_16x16x32_bf16(
                        af[kk], bfr[os * 4 + kk], acc[ts][os], 0, 0, 0);
        }
    }

    // ---- epilogue: acc -> swizzled fp32 LDS -> packed y16 stores + row stats ----
    __syncthreads();
    float* ep = (float*)smem;            // 32 rows x 128 cols fp32 = 16 KB
#pragma unroll
    for (int os = 0; os < 2; os++) {
        int colb = wv * 32 + os * 16 + r15;
        float bias = conv_b[g * Cg + colb];
#pragma unroll
        for (int ts = 0; ts < 2; ts++)
#pragma unroll
            for (int j = 0; j < 4; j++) {
                int row = ts * 16 + q * 4 + j;
                ep[row * 128 + (colb ^ ((row & 7) << 2))] = acc[ts][os][j] + bias;
            }
    }
    __syncthreads();
    int row = tid >> 3, c0 = (tid & 7) * 16;
    int sw = (row & 7) << 2;
    float4 v0 = *(const float4*)&ep[row * 128 + ((c0 + 0) ^ sw)];
    float4 v1 = *(const float4*)&ep[row * 128 + ((c0 + 4) ^ sw)];
    float4 v2 = *(const float4*)&ep[row * 128 + ((c0 + 8) ^ sw)];
    float4 v3 = *(const float4*)&ep[row * 128 + ((c0 + 12) ^ sw)];
    ushort* yp = y16 + (size_t)(b * Tdim + t0 + row) * Wdim + g * Cg + c0;
    uint4 o0, o1;
    o0.x = pack2bf(v0.x, v0.y); o0.y = pack2bf(v0.z, v0.w);
    o0.z = pack2bf(v1.x, v1.y); o0.w = pack2bf(v1.z, v1.w);
    o1.x = pack2bf(v2.x, v2.y); o1.y = pack2bf(v2.z, v2.w);
    o1.z = pack2bf(v3.x, v3.y); o1.w = pack2bf(v3.z, v3.w);
    *(uint4*)yp = o0;
    *(uint4*)(yp + 8) = o1;
    float s_part = v0.x + v0.y + v0.z + v0.w + v1.x + v1.y + v1.z + v1.w
                 + v2.x + v2.y + v2.z + v2.w + v3.x + v3.y + v3.z + v3.w;
    float q_part = v0.x * v0.x + v0.y * v0.y + v0.z * v0.z + v0.w * v0.w
                 + v1.x * v1.x + v1.y * v1.y + v1.z * v1.z + v1.w * v1.w
                 + v2.x * v2.x + v2.y * v2.y + v2.z * v2.z + v2.w * v2.w
                 + v3.x * v3.x + v3.y * v3.y + v3.z * v3.z + v3.w * v3.w;
    s_part += __shfl_xor(s_part, 1); s_part += __shfl_xor(s_part, 2);
    s_part += __shfl_xor(s_part, 4);
    q_part += __shfl_xor(q_part, 1); q_part += __shfl_xor(q_part, 2);
    q_part += __shfl_xor(q_part, 4);
    if ((tid & 7) == 0) {
        atomicAdd(&rowstat[(b * Tdim + t0 + row) * 2 + 0], s_part);
        atomicAdd(&rowstat[(b * Tdim + t0 + row) * 2 + 1], q_part);
    }
}

// ---------------- K3: streaming LN-pool -> 32 per-chunk partials (no atomics) ----------------
// grid = Bdim*32; block handles 64 rows; thread owns 4 channels
__global__ __launch_bounds__(256) void k_lnpool(const ushort* __restrict__ y16,
                                                const int* __restrict__ mask,
                                                const float* __restrict__ rowstat,
                                                float* __restrict__ part) {
    int blk = blockIdx.x;
    int b = blk >> 5, ch = blk & 31;
    int tid = threadIdx.x;
    int c0 = tid * 4;
    float a0 = 0.f, a1 = 0.f, a2 = 0.f, a3 = 0.f;
#pragma unroll 4
    for (int i = 0; i < 64; i++) {
        int t = ch * 64 + i;
        if (mask[b * Tdim + t]) continue;          // block-uniform branch
        float2 st = *(const float2*)(rowstat + (b * Tdim + t) * 2);
        float mu = st.x * (1.f / Wdim);
        float inv = rsqrtf(st.y * (1.f / Wdim) - mu * mu + 1e-5f);
        uint2 u = *(const uint2*)(y16 + (size_t)(b * Tdim + t) * Wdim + c0);
        float v0 = __uint_as_float(u.x << 16);
        float v1 = __uint_as_float(u.x & 0xffff0000u);
        float v2 = __uint_as_float(u.y << 16);
        float v3 = __uint_as_float(u.y & 0xffff0000u);
        a0 += (v0 - mu) * inv; a1 += (v1 - mu) * inv;
        a2 += (v2 - mu) * inv; a3 += (v3 - mu) * inv;
    }
    *(float4*)(part + (size_t)blk * Wdim + c0) = (float4){a0, a1, a2, a3};
}

// ---------------- K4: SE MLP + final projection -> out[b] ----------------
__global__ __launch_bounds__(256) void k_sefinal(const float* __restrict__ part,
                                                 const int* __restrict__ mask,
                                                 const float* __restrict__ ln_g,
                                                 const float* __restrict__ ln_b,
                                                 const float* __restrict__ w1,
                                                 const float* __restrict__ b1,
                                                 const float* __restrict__ w2,
                                                 const float* __restrict__ b2,
                                                 const float* __restrict__ projw,
                                                 const float* __restrict__ projb,
                                                 float* __restrict__ out) {
    int b = blockIdx.x, tid = threadIdx.x;
    __shared__ float s[Wdim];
    __shared__ float hred[4][Hdim];
    __shared__ float hid[Hdim];
    __shared__ float rbuf[4];
    __shared__ float sLinv;
    int lane = tid & 63, wv = tid >> 6;

    int cnt = 0;
    for (int t = tid; t < Tdim; t += 256) cnt += (mask[b * Tdim + t] ? 0 : 1);
    float fc = (float)cnt;
#pragma unroll
    for (int off = 32; off > 0; off >>= 1) fc += __shfl_down(fc, off);
    if (lane == 0) rbuf[wv] = fc;
    __syncthreads();
    if (tid == 0) {
        float L = rbuf[0] + rbuf[1] + rbuf[2] + rbuf[3];
        sLinv = 1.f / fmaxf(L, 1.f);
    }
    __syncthreads();
    float Linv = sLinv;

    int w4 = tid * 4;
    float4 a = {0.f, 0.f, 0.f, 0.f};
    for (int chh = 0; chh < 32; chh++) {
        float4 p = *(const float4*)(part + (size_t)(b * 32 + chh) * Wdim + w4);
        a.x += p.x; a.y += p.y; a.z += p.z; a.w += p.w;
    }
    float4 gg = *(const float4*)(ln_g + w4);
    float4 bb = *(const float4*)(ln_b + w4);
    s[w4 + 0] = gg.x * (a.x * Linv) + bb.x;
    s[w4 + 1] = gg.y * (a.y * Linv) + bb.y;
    s[w4 + 2] = gg.z * (a.z * Linv) + bb.z;
    s[w4 + 3] = gg.w * (a.w * Linv) + bb.w;
    __syncthreads();

    int j = tid & 63, p = tid >> 6;
    float ha = 0.f;
    for (int w = p * 256; w < (p + 1) * 256; ++w) ha += s[w] * w1[(size_t)w * Hdim + j];
    hred[p][j] = ha;
    __syncthreads();
    if (tid < Hdim)
        hid[tid] = fmaxf(hred[0][tid] + hred[1][tid] + hred[2][tid] + hred[3][tid] + b1[tid], 0.f);
    __syncthreads();

    float part2 = 0.f;
    for (int w = tid; w < Wdim; w += 256) {
        float ga = b2[w];
#pragma unroll 8
        for (int j2 = 0; j2 < Hdim; j2++) ga += hid[j2] * w2[(size_t)j2 * Wdim + w];
        float gate = 1.f / (1.f + expf(-ga));
        part2 += s[w] * gate * projw[w];
    }
#pragma unroll
    for (int off = 32; off > 0; off >>= 1) part2 += __shfl_down(part2, off);
    __syncthreads();
    if (lane == 0) rbuf[wv] = part2;
    __syncthreads();
    if (tid == 0) out[b] = rbuf[0] + rbuf[1] + rbuf[2] + rbuf[3] + projb[0];
}

extern "C" void kernel_launch(void* const* d_in, const int* in_sizes, int n_in,
                              void* d_out, int out_size, void* d_ws, size_t ws_size,
                              hipStream_t stream) {
    const float* h        = (const float*)d_in[0];
    const int*   mask     = (const int*)d_in[1];
    const float* offset_w = (const float*)d_in[2];
    const float* offset_b = (const float*)d_in[3];
    const float* conv_w   = (const float*)d_in[4];
    const float* conv_b   = (const float*)d_in[5];
    const float* ln_g     = (const float*)d_in[6];
    const float* ln_b     = (const float*)d_in[7];
    const float* se_w1    = (const float*)d_in[8];
    const float* se_b1    = (const float*)d_in[9];
    const float* se_w2    = (const float*)d_in[10];
    const float* se_b2    = (const float*)d_in[11];
    const float* proj_w   = (const float*)d_in[12];
    const float* proj_b   = (const float*)d_in[13];
    float* out = (float*)d_out;

    char* wsb = (char*)d_ws;
    float*  pos     = (float*)(wsb);                    //    229,376 B
    ushort* h16     = (ushort*)(wsb + 229376);          // 16,777,216 B
    short*  Wtb     = (short*)(wsb + 17006592);         //  1,835,008 B
    ushort* y16     = (ushort*)(wsb + 18841600);        // 16,777,216 B
    float*  rowstat = (float*)(wsb + 35618816);         //     65,536 B
    float*  part    = (float*)(wsb + 35684352);         //    524,288 B (total ~36.2 MB)

    k_pre<<<dim3(448 + Bdim * Tdim / 4), dim3(256), 0, stream>>>(conv_w, Wtb, h, offset_w,
                                                                 offset_b, pos, h16, rowstat);
    k_conv<<<dim3(Bdim * (Tdim / TT) * Gdim), dim3(256), 0, stream>>>(h16, Wtb, conv_b,
                                                                      pos, y16, rowstat);
    k_lnpool<<<dim3(Bdim * 32), dim3(256), 0, stream>>>(y16, mask, rowstat, part);
    k_sefinal<<<dim3(Bdim), dim3(256), 0, stream>>>(part, mask, ln_g, ln_b,
                                                    se_w1, se_b1, se_w2, se_b2,
                                                    proj_w, proj_b, out);
}

// Round 13
// 102.045 us; speedup vs baseline: 1.3224x; 1.3224x over previous
//
#include <hip/hip_runtime.h>
#include <hip/hip_bf16.h>

#define Bdim 4
#define Tdim 2048
#define Wdim 1024
#define Kdim 7
#define Gdim 8
#define Cg   128
#define Hdim 64   // W / SE_R
#define TT   64   // t-rows per conv block

typedef __attribute__((ext_vector_type(8))) short short8v;
typedef __attribute__((ext_vector_type(4))) float float4v;

__device__ __forceinline__ short f2bf(float x) {          // RNE
    union { float f; unsigned u; } v; v.f = x;
    unsigned r = v.u + 0x7fff + ((v.u >> 16) & 1);
    return (short)(r >> 16);
}

__device__ __forceinline__ unsigned pack2bf(float lo, float hi) {  // round-half-up
    return __builtin_amdgcn_perm(__float_as_uint(hi) + 0x8000u,
                                 __float_as_uint(lo) + 0x8000u, 0x07060302u);
}

// lerp two bf16x8 (as uint4) in fp32, repack to bf16x8
__device__ __forceinline__ short8v lerp_pack(uint4 a, uint4 b, float f) {
    union { uint4 u; short8v s; } r;
    const unsigned* pa = (const unsigned*)&a;
    const unsigned* pb = (const unsigned*)&b;
    unsigned* pr = (unsigned*)&r.u;
#pragma unroll
    for (int d = 0; d < 4; d++) {
        float alo = __uint_as_float(pa[d] << 16);
        float ahi = __uint_as_float(pa[d] & 0xffff0000u);
        float blo = __uint_as_float(pb[d] << 16);
        float bhi = __uint_as_float(pb[d] & 0xffff0000u);
        float rlo = alo + f * (blo - alo);
        float rhi = ahi + f * (bhi - ahi);
        pr[d] = pack2bf(rlo, rhi);
    }
    return r.s;
}

// ---------------- K_pre: weights->bf16 linear + zero rowstat + offsets GEMV (LDS-staged) + h->bf16 ----------------
__global__ __launch_bounds__(256) void k_pre(const float* __restrict__ conv_w,
                                             short* __restrict__ Wtb,
                                             const float* __restrict__ h,
                                             const float* __restrict__ offset_w,
                                             const float* __restrict__ offset_b,
                                             float* __restrict__ pos,
                                             ushort* __restrict__ h16,
                                             float* __restrict__ rowstat) {
    int tid = threadIdx.x;
    if (blockIdx.x < 448) {
        if (blockIdx.x < 64) rowstat[blockIdx.x * 256 + tid] = 0.f;
        int i = blockIdx.x * 256 + tid;
        int cb = i & 15;
        int o = (i >> 4) & 127;
        int gk = i >> 11;                            // g*7 + k
        int k = gk % Kdim, g = gk / Kdim;
        const float* src = conv_w + ((size_t)(g * Cg + o) * Cg + cb * 8) * Kdim + k;
        short8v pk;
#pragma unroll
        for (int j = 0; j < 8; j++) pk[j] = f2bf(src[(size_t)j * Kdim]);
        short8v* Wtb8 = (short8v*)Wtb;
        Wtb8[(size_t)gk * 2048 + o * 16 + cb] = pk;   // linear layout
        return;
    }
    // ---- offsets + h16: 512 blocks x 16 rows; offset_w transposed into LDS ----
    __shared__ float ow_t[Kdim * Wdim];              // 28 KB, [k][c]
    int lane = tid & 63, wv = tid >> 6;
    for (int u = tid; u < Kdim * Wdim; u += 256) {
        int c = u / Kdim, k = u - c * Kdim;          // offset_w is [c][k]
        ow_t[k * Wdim + c] = offset_w[u];
    }
    __syncthreads();
    int base = (blockIdx.x - 448) * 16 + wv * 4;
#pragma unroll 1
    for (int i = 0; i < 4; i++) {
        int bt = base + i;
        int t = bt & (Tdim - 1);
        const float* hrow = h + (size_t)bt * Wdim;
        float acc[Kdim];
#pragma unroll
        for (int k = 0; k < Kdim; k++) acc[k] = 0.f;
#pragma unroll
        for (int j = 0; j < 4; j++) {
            int c = lane * 4 + j * 256;
            float4 hv = *(const float4*)(hrow + c);
#pragma unroll
            for (int k = 0; k < Kdim; k++) {
                float4 wk = *(const float4*)&ow_t[k * Wdim + c];
                acc[k] += hv.x * wk.x + hv.y * wk.y + hv.z * wk.z + hv.w * wk.w;
            }
            ushort4 hp;
            hp.x = (ushort)f2bf(hv.x); hp.y = (ushort)f2bf(hv.y);
            hp.z = (ushort)f2bf(hv.z); hp.w = (ushort)f2bf(hv.w);
            *(ushort4*)(h16 + (size_t)bt * Wdim + c) = hp;
        }
#pragma unroll
        for (int k = 0; k < Kdim; k++) {
#pragma unroll
            for (int m = 32; m > 0; m >>= 1) acc[k] += __shfl_xor(acc[k], m);
        }
        if (lane == 0) {
#pragma unroll
            for (int k = 0; k < Kdim; k++) {
                float o = acc[k] + offset_b[k];
                float bs = (float)t + (float)(k - 3);
                float p = fminf(fmaxf(bs + o, 0.f), (float)(Tdim - 1));
                pos[bt * Kdim + k] = p;
            }
        }
    }
}

// ---------------- K2: deformable grouped conv (proven 48us structure, unchanged) ----------------
// grid: (b*32 + tc)*8 + g ; 256 thr = 4 waves; wave = 64t x 32o
__global__ __launch_bounds__(256, 4) void k_conv(const ushort* __restrict__ h16,
                                                 const short* __restrict__ Wtb,
                                                 const float* __restrict__ conv_b,
                                                 const float* __restrict__ pos,
                                                 ushort* __restrict__ y16,
                                                 float* __restrict__ rowstat) {
    __shared__ short8v sA8[2][TT * 16];   // 2 x 16 KB
    __shared__ float posl[TT * 8];        // 2 KB

    int blk = blockIdx.x;
    int g  = blk & 7;
    int tc = (blk >> 3) & 31;
    int b  = blk >> 8;
    int t0 = tc * TT;
    int tid = threadIdx.x;
    int lane = tid & 63, wv = tid >> 6;
    int r15 = lane & 15, q = lane >> 4;

    const ushort* hb = h16 + (size_t)(b * Tdim) * Wdim + g * Cg;
    const short8v* WtbV = (const short8v*)Wtb + (size_t)(g * Kdim) * 2048;

    int scb = tid & 15;          // staging col-block (16B units)
    int sr0 = tid >> 4;          // staging base row (0..15)

    // pos tile -> LDS
    {
        int base = (b * Tdim + t0) * Kdim;
        for (int u = tid; u < TT * Kdim; u += 256) {
            int r = u / 7, kk = u - r * 7;
            posl[r * 8 + kk] = pos[base + u];
        }
    }
    __syncthreads();

    float4v acc[4][2];
#pragma unroll
    for (int tt = 0; tt < 4; tt++)
#pragma unroll
        for (int n = 0; n < 2; n++) acc[tt][n] = (float4v){0.f, 0.f, 0.f, 0.f};

    // prologue: issue gather(0)
    float fr[4];
    uint4 glo[4], ghi[4];
#pragma unroll
    for (int i = 0; i < 4; i++) {
        int r = sr0 + i * 16;
        float p = posl[r * 8 + 0];
        int p0 = (int)p;
        fr[i] = p - (float)p0;
        int p1 = min(p0 + 1, Tdim - 1);
        glo[i] = *(const uint4*)(hb + (size_t)p0 * Wdim + scb * 8);
        ghi[i] = *(const uint4*)(hb + (size_t)p1 * Wdim + scb * 8);
    }

#pragma unroll 1
    for (int k = 0; k < Kdim; k++) {
        // ---- B(k) fragment loads (L2; land under lerp + barrier) ----
        short8v bfr[8];
#pragma unroll
        for (int n = 0; n < 2; n++)
#pragma unroll
            for (int kk = 0; kk < 4; kk++)
                bfr[n * 4 + kk] =
                    WtbV[(size_t)k * 2048 + (wv * 32 + n * 16 + r15) * 16 + kk * 4 + q];
        // ---- lerp + ds_write A(k) from in-flight regs ----
        short8v* buf = sA8[k & 1];
#pragma unroll
        for (int i = 0; i < 4; i++) {
            int r = sr0 + i * 16;
            buf[r * 16 + (scb ^ (r & 7))] = lerp_pack(glo[i], ghi[i], fr[i]);
        }
        __syncthreads();
        // ---- issue gather(k+1) (hides under compute(k)) ----
        if (k < Kdim - 1) {
#pragma unroll
            for (int i = 0; i < 4; i++) {
                int r = sr0 + i * 16;
                float p = posl[r * 8 + k + 1];
                int p0 = (int)p;
                fr[i] = p - (float)p0;
                int p1 = min(p0 + 1, Tdim - 1);
                glo[i] = *(const uint4*)(hb + (size_t)p0 * Wdim + scb * 8);
                ghi[i] = *(const uint4*)(hb + (size_t)p1 * Wdim + scb * 8);
            }
        }
        // ---- compute(k): 4 t-tiles x (4 ds_read + 8 MFMA) ----
#pragma unroll
        for (int tt = 0; tt < 4; tt++) {
            int r = tt * 16 + r15;
            short8v af[4];
#pragma unroll
            for (int kk = 0; kk < 4; kk++)
                af[kk] = buf[r * 16 + ((kk * 4 + q) ^ (r & 7))];
#pragma unroll
            for (int kk = 0; kk < 4; kk++) {
#pragma unroll
                for (int n = 0; n < 2; n++)
                    acc[tt][n] = __builtin_amdgcn_mfma_f32_16x16x32_bf16(
                        af[kk], bfr[n * 4 + kk], acc[tt][n], 0, 0, 0);
            }
        }
    }
    // ---- epilogue: acc -> swizzled fp32 LDS -> packed y16 stores + row stats ----
    __syncthreads();
    float* ep = (float*)sA8;     // 32 KB = 64 rows x 128 cols fp32
#pragma unroll
    for (int n = 0; n < 2; n++) {
        int colb = wv * 32 + n * 16 + r15;
        float bias = conv_b[g * Cg + colb];
#pragma unroll
        for (int tt = 0; tt < 4; tt++)
#pragma unroll
            for (int j = 0; j < 4; j++) {
                int row = tt * 16 + q * 4 + j;
                ep[row * 128 + (colb ^ ((row & 7) << 2))] = acc[tt][n][j] + bias;
            }
    }
    __syncthreads();
    int row = tid >> 2, c0 = (tid & 3) * 32;
    int sw = (row & 7) << 2;
    ushort* yp = y16 + (size_t)(b * Tdim + t0 + row) * Wdim + g * Cg + c0;
    float s_part = 0.f, q_part = 0.f;
#pragma unroll
    for (int s = 0; s < 4; s++) {
        float4 va = *(const float4*)&ep[row * 128 + ((c0 + s * 8) ^ sw)];
        float4 vb = *(const float4*)&ep[row * 128 + ((c0 + s * 8 + 4) ^ sw)];
        s_part += va.x + va.y + va.z + va.w + vb.x + vb.y + vb.z + vb.w;
        q_part += va.x * va.x + va.y * va.y + va.z * va.z + va.w * va.w
                + vb.x * vb.x + vb.y * vb.y + vb.z * vb.z + vb.w * vb.w;
        uint4 o;
        o.x = pack2bf(va.x, va.y);
        o.y = pack2bf(va.z, va.w);
        o.z = pack2bf(vb.x, vb.y);
        o.w = pack2bf(vb.z, vb.w);
        *(uint4*)(yp + s * 8) = o;
    }
    s_part += __shfl_xor(s_part, 1); s_part += __shfl_xor(s_part, 2);
    q_part += __shfl_xor(q_part, 1); q_part += __shfl_xor(q_part, 2);
    if ((tid & 3) == 0) {
        atomicAdd(&rowstat[(b * Tdim + t0 + row) * 2 + 0], s_part);
        atomicAdd(&rowstat[(b * Tdim + t0 + row) * 2 + 1], q_part);
    }
}

// ---------------- K3: streaming LN-pool -> 64 per-chunk partials (no atomics) ----------------
// grid = Bdim*64; block handles 32 rows; thread owns 4 channels
__global__ __launch_bounds__(256) void k_lnpool(const ushort* __restrict__ y16,
                                                const int* __restrict__ mask,
                                                const float* __restrict__ rowstat,
                                                float* __restrict__ part) {
    int blk = blockIdx.x;
    int b = blk >> 6, ch = blk & 63;
    int tid = threadIdx.x;
    int c0 = tid * 4;
    float a0 = 0.f, a1 = 0.f, a2 = 0.f, a3 = 0.f;
#pragma unroll 4
    for (int i = 0; i < 32; i++) {
        int t = ch * 32 + i;
        if (mask[b * Tdim + t]) continue;          // block-uniform branch
        float2 st = *(const float2*)(rowstat + (b * Tdim + t) * 2);
        float mu = st.x * (1.f / Wdim);
        float inv = rsqrtf(st.y * (1.f / Wdim) - mu * mu + 1e-5f);
        uint2 u = *(const uint2*)(y16 + (size_t)(b * Tdim + t) * Wdim + c0);
        float v0 = __uint_as_float(u.x << 16);
        float v1 = __uint_as_float(u.x & 0xffff0000u);
        float v2 = __uint_as_float(u.y << 16);
        float v3 = __uint_as_float(u.y & 0xffff0000u);
        a0 += (v0 - mu) * inv; a1 += (v1 - mu) * inv;
        a2 += (v2 - mu) * inv; a3 += (v3 - mu) * inv;
    }
    *(float4*)(part + (size_t)blk * Wdim + c0) = (float4){a0, a1, a2, a3};
}

// ---------------- K4: SE MLP + final projection -> out[b] ----------------
__global__ __launch_bounds__(256) void k_sefinal(const float* __restrict__ part,
                                                 const int* __restrict__ mask,
                                                 const float* __restrict__ ln_g,
                                                 const float* __restrict__ ln_b,
                                                 const float* __restrict__ w1,
                                                 const float* __restrict__ b1,
                                                 const float* __restrict__ w2,
                                                 const float* __restrict__ b2,
                                                 const float* __restrict__ projw,
                                                 const float* __restrict__ projb,
                                                 float* __restrict__ out) {
    int b = blockIdx.x, tid = threadIdx.x;
    __shared__ float s[Wdim];
    __shared__ float hred[4][Hdim];
    __shared__ float hid[Hdim];
    __shared__ float rbuf[4];
    __shared__ float sLinv;
    int lane = tid & 63, wv = tid >> 6;

    int cnt = 0;
    for (int t = tid; t < Tdim; t += 256) cnt += (mask[b * Tdim + t] ? 0 : 1);
    float fc = (float)cnt;
#pragma unroll
    for (int off = 32; off > 0; off >>= 1) fc += __shfl_down(fc, off);
    if (lane == 0) rbuf[wv] = fc;
    __syncthreads();
    if (tid == 0) {
        float L = rbuf[0] + rbuf[1] + rbuf[2] + rbuf[3];
        sLinv = 1.f / fmaxf(L, 1.f);
    }
    __syncthreads();
    float Linv = sLinv;

    int w4 = tid * 4;
    float4 a = {0.f, 0.f, 0.f, 0.f};
    for (int chh = 0; chh < 64; chh++) {
        float4 p = *(const float4*)(part + (size_t)(b * 64 + chh) * Wdim + w4);
        a.x += p.x; a.y += p.y; a.z += p.z; a.w += p.w;
    }
    float4 gg = *(const float4*)(ln_g + w4);
    float4 bb = *(const float4*)(ln_b + w4);
    s[w4 + 0] = gg.x * (a.x * Linv) + bb.x;
    s[w4 + 1] = gg.y * (a.y * Linv) + bb.y;
    s[w4 + 2] = gg.z * (a.z * Linv) + bb.z;
    s[w4 + 3] = gg.w * (a.w * Linv) + bb.w;
    __syncthreads();

    int j = tid & 63, p = tid >> 6;
    float ha = 0.f;
    for (int w = p * 256; w < (p + 1) * 256; ++w) ha += s[w] * w1[(size_t)w * Hdim + j];
    hred[p][j] = ha;
    __syncthreads();
    if (tid < Hdim)
        hid[tid] = fmaxf(hred[0][tid] + hred[1][tid] + hred[2][tid] + hred[3][tid] + b1[tid], 0.f);
    __syncthreads();

    float part2 = 0.f;
    for (int w = tid; w < Wdim; w += 256) {
        float ga = b2[w];
#pragma unroll 8
        for (int j2 = 0; j2 < Hdim; j2++) ga += hid[j2] * w2[(size_t)j2 * Wdim + w];
        float gate = 1.f / (1.f + expf(-ga));
        part2 += s[w] * gate * projw[w];
    }
#pragma unroll
    for (int off = 32; off > 0; off >>= 1) part2 += __shfl_down(part2, off);
    __syncthreads();
    if (lane == 0) rbuf[wv] = part2;
    __syncthreads();
    if (tid == 0) out[b] = rbuf[0] + rbuf[1] + rbuf[2] + rbuf[3] + projb[0];
}

extern "C" void kernel_launch(void* const* d_in, const int* in_sizes, int n_in,
                              void* d_out, int out_size, void* d_ws, size_t ws_size,
                              hipStream_t stream) {
    const float* h        = (const float*)d_in[0];
    const int*   mask     = (const int*)d_in[1];
    const float* offset_w = (const float*)d_in[2];
    const float* offset_b = (const float*)d_in[3];
    const float* conv_w   = (const float*)d_in[4];
    const float* conv_b   = (const float*)d_in[5];
    const float* ln_g     = (const float*)d_in[6];
    const float* ln_b     = (const float*)d_in[7];
    const float* se_w1    = (const float*)d_in[8];
    const float* se_b1    = (const float*)d_in[9];
    const float* se_w2    = (const float*)d_in[10];
    const float* se_b2    = (const float*)d_in[11];
    const float* proj_w   = (const float*)d_in[12];
    const float* proj_b   = (const float*)d_in[13];
    float* out = (float*)d_out;

    char* wsb = (char*)d_ws;
    float*  pos     = (float*)(wsb);                    //    229,376 B
    ushort* h16     = (ushort*)(wsb + 229376);          // 16,777,216 B
    short*  Wtb     = (short*)(wsb + 17006592);         //  1,835,008 B
    ushort* y16     = (ushort*)(wsb + 18841600);        // 16,777,216 B
    float*  rowstat = (float*)(wsb + 35618816);         //     65,536 B
    float*  part    = (float*)(wsb + 35684352);         //  1,048,576 B (total ~36.7 MB)

    k_pre<<<dim3(448 + 512), dim3(256), 0, stream>>>(conv_w, Wtb, h, offset_w,
                                                     offset_b, pos, h16, rowstat);
    k_conv<<<dim3(Bdim * (Tdim / TT) * Gdim), dim3(256), 0, stream>>>(h16, Wtb, conv_b,
                                                                      pos, y16, rowstat);
    k_lnpool<<<dim3(Bdim * 64), dim3(256), 0, stream>>>(y16, mask, rowstat, part);
    k_sefinal<<<dim3(Bdim), dim3(256), 0, stream>>>(part, mask, ln_g, ln_b,
                                                    se_w1, se_b1, se_w2, se_b2,
                                                    proj_w, proj_b, out);
}

// Round 14
// 101.955 us; speedup vs baseline: 1.3236x; 1.0009x over previous
//
#include <hip/hip_runtime.h>
#include <hip/hip_bf16.h>

#define Bdim 4
#define Tdim 2048
#define Wdim 1024
#define Kdim 7
#define Gdim 8
#define Cg   128
#define Hdim 64   // W / SE_R
#define TT   64   // t-rows per conv block

typedef __attribute__((ext_vector_type(8))) short short8v;
typedef __attribute__((ext_vector_type(4))) float float4v;

__device__ __forceinline__ short f2bf(float x) {          // RNE
    union { float f; unsigned u; } v; v.f = x;
    unsigned r = v.u + 0x7fff + ((v.u >> 16) & 1);
    return (short)(r >> 16);
}

__device__ __forceinline__ unsigned pack2bf(float lo, float hi) {  // round-half-up
    return __builtin_amdgcn_perm(__float_as_uint(hi) + 0x8000u,
                                 __float_as_uint(lo) + 0x8000u, 0x07060302u);
}

// lerp two bf16x8 (as uint4) in fp32, repack to bf16x8
__device__ __forceinline__ short8v lerp_pack(uint4 a, uint4 b, float f) {
    union { uint4 u; short8v s; } r;
    const unsigned* pa = (const unsigned*)&a;
    const unsigned* pb = (const unsigned*)&b;
    unsigned* pr = (unsigned*)&r.u;
#pragma unroll
    for (int d = 0; d < 4; d++) {
        float alo = __uint_as_float(pa[d] << 16);
        float ahi = __uint_as_float(pa[d] & 0xffff0000u);
        float blo = __uint_as_float(pb[d] << 16);
        float bhi = __uint_as_float(pb[d] & 0xffff0000u);
        float rlo = alo + f * (blo - alo);
        float rhi = ahi + f * (bhi - ahi);
        pr[d] = pack2bf(rlo, rhi);
    }
    return r.s;
}

// ---------------- K_pre: weights->bf16 linear + zero rowstat + offsets GEMV (LDS-staged) + h->bf16 ----------------
__global__ __launch_bounds__(256) void k_pre(const float* __restrict__ conv_w,
                                             short* __restrict__ Wtb,
                                             const float* __restrict__ h,
                                             const float* __restrict__ offset_w,
                                             const float* __restrict__ offset_b,
                                             float* __restrict__ pos,
                                             ushort* __restrict__ h16,
                                             float* __restrict__ rowstat) {
    int tid = threadIdx.x;
    if (blockIdx.x < 448) {
        if (blockIdx.x < 64) rowstat[blockIdx.x * 256 + tid] = 0.f;
        int i = blockIdx.x * 256 + tid;
        int cb = i & 15;
        int o = (i >> 4) & 127;
        int gk = i >> 11;                            // g*7 + k
        int k = gk % Kdim, g = gk / Kdim;
        const float* src = conv_w + ((size_t)(g * Cg + o) * Cg + cb * 8) * Kdim + k;
        short8v pk;
#pragma unroll
        for (int j = 0; j < 8; j++) pk[j] = f2bf(src[(size_t)j * Kdim]);
        short8v* Wtb8 = (short8v*)Wtb;
        Wtb8[(size_t)gk * 2048 + o * 16 + cb] = pk;   // linear layout
        return;
    }
    // ---- offsets + h16: 512 blocks x 16 rows; offset_w transposed into LDS ----
    __shared__ float ow_t[Kdim * Wdim];              // 28 KB, [k][c]
    int lane = tid & 63, wv = tid >> 6;
    for (int u = tid; u < Kdim * Wdim; u += 256) {
        int c = u / Kdim, k = u - c * Kdim;          // offset_w is [c][k]
        ow_t[k * Wdim + c] = offset_w[u];
    }
    __syncthreads();
    int base = (blockIdx.x - 448) * 16 + wv * 4;
#pragma unroll 1
    for (int i = 0; i < 4; i++) {
        int bt = base + i;
        int t = bt & (Tdim - 1);
        const float* hrow = h + (size_t)bt * Wdim;
        float acc[Kdim];
#pragma unroll
        for (int k = 0; k < Kdim; k++) acc[k] = 0.f;
#pragma unroll
        for (int j = 0; j < 4; j++) {
            int c = lane * 4 + j * 256;
            float4 hv = *(const float4*)(hrow + c);
#pragma unroll
            for (int k = 0; k < Kdim; k++) {
                float4 wk = *(const float4*)&ow_t[k * Wdim + c];
                acc[k] += hv.x * wk.x + hv.y * wk.y + hv.z * wk.z + hv.w * wk.w;
            }
            ushort4 hp;
            hp.x = (ushort)f2bf(hv.x); hp.y = (ushort)f2bf(hv.y);
            hp.z = (ushort)f2bf(hv.z); hp.w = (ushort)f2bf(hv.w);
            *(ushort4*)(h16 + (size_t)bt * Wdim + c) = hp;
        }
#pragma unroll
        for (int k = 0; k < Kdim; k++) {
#pragma unroll
            for (int m = 32; m > 0; m >>= 1) acc[k] += __shfl_xor(acc[k], m);
        }
        if (lane == 0) {
#pragma unroll
            for (int k = 0; k < Kdim; k++) {
                float o = acc[k] + offset_b[k];
                float bs = (float)t + (float)(k - 3);
                float p = fminf(fmaxf(bs + o, 0.f), (float)(Tdim - 1));
                pos[bt * Kdim + k] = p;
            }
        }
    }
}

// ---------------- K2: deformable grouped conv (proven 48us structure, unchanged) ----------------
// grid: (b*32 + tc)*8 + g ; 256 thr = 4 waves; wave = 64t x 32o
__global__ __launch_bounds__(256, 4) void k_conv(const ushort* __restrict__ h16,
                                                 const short* __restrict__ Wtb,
                                                 const float* __restrict__ conv_b,
                                                 const float* __restrict__ pos,
                                                 ushort* __restrict__ y16,
                                                 float* __restrict__ rowstat) {
    __shared__ short8v sA8[2][TT * 16];   // 2 x 16 KB
    __shared__ float posl[TT * 8];        // 2 KB

    int blk = blockIdx.x;
    int g  = blk & 7;
    int tc = (blk >> 3) & 31;
    int b  = blk >> 8;
    int t0 = tc * TT;
    int tid = threadIdx.x;
    int lane = tid & 63, wv = tid >> 6;
    int r15 = lane & 15, q = lane >> 4;

    const ushort* hb = h16 + (size_t)(b * Tdim) * Wdim + g * Cg;
    const short8v* WtbV = (const short8v*)Wtb + (size_t)(g * Kdim) * 2048;

    int scb = tid & 15;          // staging col-block (16B units)
    int sr0 = tid >> 4;          // staging base row (0..15)

    // pos tile -> LDS
    {
        int base = (b * Tdim + t0) * Kdim;
        for (int u = tid; u < TT * Kdim; u += 256) {
            int r = u / 7, kk = u - r * 7;
            posl[r * 8 + kk] = pos[base + u];
        }
    }
    __syncthreads();

    float4v acc[4][2];
#pragma unroll
    for (int tt = 0; tt < 4; tt++)
#pragma unroll
        for (int n = 0; n < 2; n++) acc[tt][n] = (float4v){0.f, 0.f, 0.f, 0.f};

    // prologue: issue gather(0)
    float fr[4];
    uint4 glo[4], ghi[4];
#pragma unroll
    for (int i = 0; i < 4; i++) {
        int r = sr0 + i * 16;
        float p = posl[r * 8 + 0];
        int p0 = (int)p;
        fr[i] = p - (float)p0;
        int p1 = min(p0 + 1, Tdim - 1);
        glo[i] = *(const uint4*)(hb + (size_t)p0 * Wdim + scb * 8);
        ghi[i] = *(const uint4*)(hb + (size_t)p1 * Wdim + scb * 8);
    }

#pragma unroll 1
    for (int k = 0; k < Kdim; k++) {
        // ---- B(k) fragment loads (L2; land under lerp + barrier) ----
        short8v bfr[8];
#pragma unroll
        for (int n = 0; n < 2; n++)
#pragma unroll
            for (int kk = 0; kk < 4; kk++)
                bfr[n * 4 + kk] =
                    WtbV[(size_t)k * 2048 + (wv * 32 + n * 16 + r15) * 16 + kk * 4 + q];
        // ---- lerp + ds_write A(k) from in-flight regs ----
        short8v* buf = sA8[k & 1];
#pragma unroll
        for (int i = 0; i < 4; i++) {
            int r = sr0 + i * 16;
            buf[r * 16 + (scb ^ (r & 7))] = lerp_pack(glo[i], ghi[i], fr[i]);
        }
        __syncthreads();
        // ---- issue gather(k+1) (hides under compute(k)) ----
        if (k < Kdim - 1) {
#pragma unroll
            for (int i = 0; i < 4; i++) {
                int r = sr0 + i * 16;
                float p = posl[r * 8 + k + 1];
                int p0 = (int)p;
                fr[i] = p - (float)p0;
                int p1 = min(p0 + 1, Tdim - 1);
                glo[i] = *(const uint4*)(hb + (size_t)p0 * Wdim + scb * 8);
                ghi[i] = *(const uint4*)(hb + (size_t)p1 * Wdim + scb * 8);
            }
        }
        // ---- compute(k): 4 t-tiles x (4 ds_read + 8 MFMA) ----
#pragma unroll
        for (int tt = 0; tt < 4; tt++) {
            int r = tt * 16 + r15;
            short8v af[4];
#pragma unroll
            for (int kk = 0; kk < 4; kk++)
                af[kk] = buf[r * 16 + ((kk * 4 + q) ^ (r & 7))];
#pragma unroll
            for (int kk = 0; kk < 4; kk++) {
#pragma unroll
                for (int n = 0; n < 2; n++)
                    acc[tt][n] = __builtin_amdgcn_mfma_f32_16x16x32_bf16(
                        af[kk], bfr[n * 4 + kk], acc[tt][n], 0, 0, 0);
            }
        }
    }
    // ---- epilogue: acc -> swizzled fp32 LDS -> packed y16 stores + row stats ----
    __syncthreads();
    float* ep = (float*)sA8;     // 32 KB = 64 rows x 128 cols fp32
#pragma unroll
    for (int n = 0; n < 2; n++) {
        int colb = wv * 32 + n * 16 + r15;
        float bias = conv_b[g * Cg + colb];
#pragma unroll
        for (int tt = 0; tt < 4; tt++)
#pragma unroll
            for (int j = 0; j < 4; j++) {
                int row = tt * 16 + q * 4 + j;
                ep[row * 128 + (colb ^ ((row & 7) << 2))] = acc[tt][n][j] + bias;
            }
    }
    __syncthreads();
    int row = tid >> 2, c0 = (tid & 3) * 32;
    int sw = (row & 7) << 2;
    ushort* yp = y16 + (size_t)(b * Tdim + t0 + row) * Wdim + g * Cg + c0;
    float s_part = 0.f, q_part = 0.f;
#pragma unroll
    for (int s = 0; s < 4; s++) {
        float4 va = *(const float4*)&ep[row * 128 + ((c0 + s * 8) ^ sw)];
        float4 vb = *(const float4*)&ep[row * 128 + ((c0 + s * 8 + 4) ^ sw)];
        s_part += va.x + va.y + va.z + va.w + vb.x + vb.y + vb.z + vb.w;
        q_part += va.x * va.x + va.y * va.y + va.z * va.z + va.w * va.w
                + vb.x * vb.x + vb.y * vb.y + vb.z * vb.z + vb.w * vb.w;
        uint4 o;
        o.x = pack2bf(va.x, va.y);
        o.y = pack2bf(va.z, va.w);
        o.z = pack2bf(vb.x, vb.y);
        o.w = pack2bf(vb.z, vb.w);
        *(uint4*)(yp + s * 8) = o;
    }
    s_part += __shfl_xor(s_part, 1); s_part += __shfl_xor(s_part, 2);
    q_part += __shfl_xor(q_part, 1); q_part += __shfl_xor(q_part, 2);
    if ((tid & 3) == 0) {
        atomicAdd(&rowstat[(b * Tdim + t0 + row) * 2 + 0], s_part);
        atomicAdd(&rowstat[(b * Tdim + t0 + row) * 2 + 1], q_part);
    }
}

// ---------------- K3: streaming LN-pool -> 64 per-chunk partials (no atomics) ----------------
// grid = Bdim*64; block handles 32 rows; thread owns 4 channels
__global__ __launch_bounds__(256) void k_lnpool(const ushort* __restrict__ y16,
                                                const int* __restrict__ mask,
                                                const float* __restrict__ rowstat,
                                                float* __restrict__ part) {
    int blk = blockIdx.x;
    int b = blk >> 6, ch = blk & 63;
    int tid = threadIdx.x;
    int c0 = tid * 4;
    float a0 = 0.f, a1 = 0.f, a2 = 0.f, a3 = 0.f;
#pragma unroll 4
    for (int i = 0; i < 32; i++) {
        int t = ch * 32 + i;
        if (mask[b * Tdim + t]) continue;          // block-uniform branch
        float2 st = *(const float2*)(rowstat + (b * Tdim + t) * 2);
        float mu = st.x * (1.f / Wdim);
        float inv = rsqrtf(st.y * (1.f / Wdim) - mu * mu + 1e-5f);
        uint2 u = *(const uint2*)(y16 + (size_t)(b * Tdim + t) * Wdim + c0);
        float v0 = __uint_as_float(u.x << 16);
        float v1 = __uint_as_float(u.x & 0xffff0000u);
        float v2 = __uint_as_float(u.y << 16);
        float v3 = __uint_as_float(u.y & 0xffff0000u);
        a0 += (v0 - mu) * inv; a1 += (v1 - mu) * inv;
        a2 += (v2 - mu) * inv; a3 += (v3 - mu) * inv;
    }
    *(float4*)(part + (size_t)blk * Wdim + c0) = (float4){a0, a1, a2, a3};
}

// ---------------- K4: SE MLP + final projection -> out[b] ----------------
__global__ __launch_bounds__(256) void k_sefinal(const float* __restrict__ part,
                                                 const int* __restrict__ mask,
                                                 const float* __restrict__ ln_g,
                                                 const float* __restrict__ ln_b,
                                                 const float* __restrict__ w1,
                                                 const float* __restrict__ b1,
                                                 const float* __restrict__ w2,
                                                 const float* __restrict__ b2,
                                                 const float* __restrict__ projw,
                                                 const float* __restrict__ projb,
                                                 float* __restrict__ out) {
    int b = blockIdx.x, tid = threadIdx.x;
    __shared__ float s[Wdim];
    __shared__ float hred[4][Hdim];
    __shared__ float hid[Hdim];
    __shared__ float rbuf[4];
    __shared__ float sLinv;
    int lane = tid & 63, wv = tid >> 6;

    int cnt = 0;
    for (int t = tid; t < Tdim; t += 256) cnt += (mask[b * Tdim + t] ? 0 : 1);
    float fc = (float)cnt;
#pragma unroll
    for (int off = 32; off > 0; off >>= 1) fc += __shfl_down(fc, off);
    if (lane == 0) rbuf[wv] = fc;
    __syncthreads();
    if (tid == 0) {
        float L = rbuf[0] + rbuf[1] + rbuf[2] + rbuf[3];
        sLinv = 1.f / fmaxf(L, 1.f);
    }
    __syncthreads();
    float Linv = sLinv;

    int w4 = tid * 4;
    float4 a = {0.f, 0.f, 0.f, 0.f};
    for (int chh = 0; chh < 64; chh++) {
        float4 p = *(const float4*)(part + (size_t)(b * 64 + chh) * Wdim + w4);
        a.x += p.x; a.y += p.y; a.z += p.z; a.w += p.w;
    }
    float4 gg = *(const float4*)(ln_g + w4);
    float4 bb = *(const float4*)(ln_b + w4);
    s[w4 + 0] = gg.x * (a.x * Linv) + bb.x;
    s[w4 + 1] = gg.y * (a.y * Linv) + bb.y;
    s[w4 + 2] = gg.z * (a.z * Linv) + bb.z;
    s[w4 + 3] = gg.w * (a.w * Linv) + bb.w;
    __syncthreads();

    int j = tid & 63, p = tid >> 6;
    float ha = 0.f;
    for (int w = p * 256; w < (p + 1) * 256; ++w) ha += s[w] * w1[(size_t)w * Hdim + j];
    hred[p][j] = ha;
    __syncthreads();
    if (tid < Hdim)
        hid[tid] = fmaxf(hred[0][tid] + hred[1][tid] + hred[2][tid] + hred[3][tid] + b1[tid], 0.f);
    __syncthreads();

    float part2 = 0.f;
    for (int w = tid; w < Wdim; w += 256) {
        float ga = b2[w];
#pragma unroll 8
        for (int j2 = 0; j2 < Hdim; j2++) ga += hid[j2] * w2[(size_t)j2 * Wdim + w];
        float gate = 1.f / (1.f + expf(-ga));
        part2 += s[w] * gate * projw[w];
    }
#pragma unroll
    for (int off = 32; off > 0; off >>= 1) part2 += __shfl_down(part2, off);
    __syncthreads();
    if (lane == 0) rbuf[wv] = part2;
    __syncthreads();
    if (tid == 0) out[b] = rbuf[0] + rbuf[1] + rbuf[2] + rbuf[3] + projb[0];
}

extern "C" void kernel_launch(void* const* d_in, const int* in_sizes, int n_in,
                              void* d_out, int out_size, void* d_ws, size_t ws_size,
                              hipStream_t stream) {
    const float* h        = (const float*)d_in[0];
    const int*   mask     = (const int*)d_in[1];
    const float* offset_w = (const float*)d_in[2];
    const float* offset_b = (const float*)d_in[3];
    const float* conv_w   = (const float*)d_in[4];
    const float* conv_b   = (const float*)d_in[5];
    const float* ln_g     = (const float*)d_in[6];
    const float* ln_b     = (const float*)d_in[7];
    const float* se_w1    = (const float*)d_in[8];
    const float* se_b1    = (const float*)d_in[9];
    const float* se_w2    = (const float*)d_in[10];
    const float* se_b2    = (const float*)d_in[11];
    const float* proj_w   = (const float*)d_in[12];
    const float* proj_b   = (const float*)d_in[13];
    float* out = (float*)d_out;

    char* wsb = (char*)d_ws;
    float*  pos     = (float*)(wsb);                    //    229,376 B
    ushort* h16     = (ushort*)(wsb + 229376);          // 16,777,216 B
    short*  Wtb     = (short*)(wsb + 17006592);         //  1,835,008 B
    ushort* y16     = (ushort*)(wsb + 18841600);        // 16,777,216 B
    float*  rowstat = (float*)(wsb + 35618816);         //     65,536 B
    float*  part    = (float*)(wsb + 35684352);         //  1,048,576 B (total ~36.7 MB)

    k_pre<<<dim3(448 + 512), dim3(256), 0, stream>>>(conv_w, Wtb, h, offset_w,
                                                     offset_b, pos, h16, rowstat);
    k_conv<<<dim3(Bdim * (Tdim / TT) * Gdim), dim3(256), 0, stream>>>(h16, Wtb, conv_b,
                                                                      pos, y16, rowstat);
    k_lnpool<<<dim3(Bdim * 64), dim3(256), 0, stream>>>(y16, mask, rowstat, part);
    k_sefinal<<<dim3(Bdim), dim3(256), 0, stream>>>(part, mask, ln_g, ln_b,
                                                    se_w1, se_b1, se_w2, se_b2,
                                                    proj_w, proj_b, out);
}